// Round 6
// baseline (283.444 us; speedup 1.0000x reference)
//
#include <hip/hip_runtime.h>
#include <hip/hip_bf16.h>

#define TOKENS 4096
#define IN_F   4096
#define OUT_F  4096

typedef __bf16 bf16x8 __attribute__((ext_vector_type(8)));
typedef float  f32x4  __attribute__((ext_vector_type(4)));
typedef float  f32x16 __attribute__((ext_vector_type(16)));
typedef unsigned int u32;
typedef u32 u32x4 __attribute__((ext_vector_type(4)));

#define DEQ_BLOCKS 2048   // 4096 rows * 128 thread-chunks / 256
#define CVT_BLOCKS 4096   // 4096*4096 /16 /256

__device__ __forceinline__ void gld_lds16(const void* g, void* l) {
    __builtin_amdgcn_global_load_lds(
        (const __attribute__((address_space(1))) u32*)g,
        (__attribute__((address_space(3))) u32*)l,
        16, 0, 0);
}

// ---------------------------------------------------------------------------
// Fused prep: blockIdx < DEQ_BLOCKS  -> dequant int4 W (16B qweight loads,
//             32 weights/thread, 64B contiguous store)
//             else                   -> x fp32->bf16 (16 elems/thread)
// ---------------------------------------------------------------------------
__global__ __launch_bounds__(256) void prep_kernel(
        const u32* __restrict__ qweight, const u32* __restrict__ qzeros,
        const float* __restrict__ scales, const float* __restrict__ x,
        __bf16* __restrict__ W, __bf16* __restrict__ A) {
    const int tid = threadIdx.x;
    if (blockIdx.x < DEQ_BLOCKS) {
        int idx4 = blockIdx.x * 256 + tid;      // 0 .. 524287
        int n  = idx4 >> 7;                     // out row (128 chunks/row)
        int p4 = (idx4 & 127) << 2;             // first packed col (0..508)
        int g  = p4 >> 4;                       // group id (constant over 4)
        u32 qz = qzeros[(n << 2) + (g >> 3)];
        float z = (float)((qz >> ((g & 7) * 4)) & 15);
        float s = scales[(n << 5) + g];
        u32x4 qw = *(const u32x4*)(qweight + (size_t)n * 512 + p4);
        __bf16* dst = W + (size_t)n * IN_F + p4 * 8;
#pragma unroll
        for (int c = 0; c < 4; ++c) {
            bf16x8 h;
#pragma unroll
            for (int j = 0; j < 8; ++j) {
                float w = ((float)((qw[c] >> (4 * j)) & 15) - z) * s;
                h[j] = (__bf16)w;
            }
            *(bf16x8*)(dst + c * 8) = h;
        }
    } else {
        int idx = (blockIdx.x - DEQ_BLOCKS) * 256 + tid;   // 0 .. 1048575
        const f32x4* xp = (const f32x4*)x + (size_t)idx * 4;
        f32x4 v0 = xp[0], v1 = xp[1], v2 = xp[2], v3 = xp[3];
        bf16x8 h0, h1;
#pragma unroll
        for (int j = 0; j < 4; ++j) {
            h0[j] = (__bf16)v0[j]; h0[4 + j] = (__bf16)v1[j];
            h1[j] = (__bf16)v2[j]; h1[4 + j] = (__bf16)v3[j];
        }
        bf16x8* ap = (bf16x8*)A + (size_t)idx * 2;
        ap[0] = h0; ap[1] = h1;
    }
}

// ---------------------------------------------------------------------------
// GEMM: C[m][n] = sum_k A[m][k]*B[n][k] + bias[n]   (B^T-input form)
//    128x128 tile, BK=64, 256 threads (4 waves, 2x2 of 64x64 per wave),
//    mfma_f32_32x32x16_bf16 (2382 TF ubench vs 2075 for 16x16x32) as
//    2x2 of 32x32 tiles per wave. global_load_lds width=16 staging,
//    LDS 32 KB, __launch_bounds__(256,4) -> 4 blocks/CU (verified R4/R5).
//    Swizzle: row = 8 chunks of 16B; LDS slot s of row r holds global
//    chunk s ^ (r&7). Fragment read bank-group = (2c+h)^(lane&7) ->
//    all 8 groups per 8-lane phase, conflict-free (R5: conflicts == 0).
//    Operand layout 32x32x16: A/B lane holds 8 contiguous bf16 at
//    row/col = lane&31, k = (lane>>5)*8 + e. C/D: col = lane&31,
//    row = (reg&3) + 8*(reg>>2) + 4*(lane>>5)  [learn_hip m74/m101].
// ---------------------------------------------------------------------------
__global__ __launch_bounds__(256, 4) void gemm_bt(
        const __bf16* __restrict__ A, const __bf16* __restrict__ B,
        const float* __restrict__ bias, float* __restrict__ C) {
    __shared__ __align__(16) __bf16 lsA[128 * 64];
    __shared__ __align__(16) __bf16 lsB[128 * 64];

    const int t      = threadIdx.x;
    const int bm     = blockIdx.y, bn = blockIdx.x;
    const int lane   = t & 63, wave = t >> 6;
    const int wm     = (wave >> 1) * 64;
    const int wn     = (wave & 1) * 64;
    const int lane31 = lane & 31;
    const int half   = lane >> 5;          // k-half within 16

    const __bf16* Abase = A + (size_t)bm * 128 * IN_F;
    const __bf16* Bbase = B + (size_t)bn * 128 * IN_F;

    // staging: 128x64 tile = 1024 x 16B chunks; thread t does chunks
    // t+256*u (u=0..3). chunk q -> row q>>3, slot q&7; fetch global chunk
    // (q&7) ^ (row&7). LDS dest contiguous (q*16), as global_load_lds needs.
    int srow[4], scol[4];
#pragma unroll
    for (int u = 0; u < 4; ++u) {
        int q = t + u * 256;
        srow[u] = q >> 3;
        scol[u] = ((q & 7) ^ ((q >> 3) & 7)) * 8;
    }

    f32x16 acc[2][2] = {};

    for (int k0 = 0; k0 < IN_F; k0 += 64) {
#pragma unroll
        for (int u = 0; u < 4; ++u) {
            int q = t + u * 256;
            gld_lds16(Abase + (size_t)srow[u] * IN_F + k0 + scol[u],
                      (char*)lsA + q * 16);
            gld_lds16(Bbase + (size_t)srow[u] * IN_F + k0 + scol[u],
                      (char*)lsB + q * 16);
        }
        __syncthreads();

#pragma unroll
        for (int c = 0; c < 4; ++c) {           // k-chunk of 16 within BK=64
            const int ci = c * 2 + half;        // 16B-chunk index in row
            bf16x8 af[2], bf[2];
#pragma unroll
            for (int i = 0; i < 2; ++i) {
                const int Ra = wm + i * 32 + lane31;
                const int Rb = wn + i * 32 + lane31;
                af[i] = *(const bf16x8*)(lsA + Ra * 64 + ((ci ^ (Ra & 7)) * 8));
                bf[i] = *(const bf16x8*)(lsB + Rb * 64 + ((ci ^ (Rb & 7)) * 8));
            }
#pragma unroll
            for (int i = 0; i < 2; ++i)
#pragma unroll
                for (int j = 0; j < 2; ++j)
                    acc[i][j] = __builtin_amdgcn_mfma_f32_32x32x16_bf16(
                        af[i], bf[j], acc[i][j], 0, 0, 0);
        }
        __syncthreads();
    }

    // epilogue: col = lane&31, row = (reg&3) + 8*(reg>>2) + 4*half
    const int row_base = bm * 128 + wm;
    const int col_base = bn * 128 + wn;
#pragma unroll
    for (int tj = 0; tj < 2; ++tj) {
        const int col = col_base + tj * 32 + lane31;
        const float bv = bias[col];
#pragma unroll
        for (int ti = 0; ti < 2; ++ti) {
            const int rb = row_base + ti * 32 + 4 * half;
#pragma unroll
            for (int reg = 0; reg < 16; ++reg) {
                const int row = rb + (reg & 3) + 8 * (reg >> 2);
                C[(size_t)row * OUT_F + col] = acc[ti][tj][reg] + bv;
            }
        }
    }
}

extern "C" void kernel_launch(void* const* d_in, const int* in_sizes, int n_in,
                              void* d_out, int out_size, void* d_ws, size_t ws_size,
                              hipStream_t stream) {
    (void)in_sizes; (void)n_in; (void)out_size; (void)ws_size;
    const float* x       = (const float*)d_in[0];
    const u32*   qweight = (const u32*)d_in[1];
    const u32*   qzeros  = (const u32*)d_in[2];
    const float* scales  = (const float*)d_in[3];
    const float* bias    = (const float*)d_in[4];
    float* out = (float*)d_out;

    __bf16* W   = (__bf16*)d_ws;                                     // 32 MB
    __bf16* Abf = (__bf16*)((char*)d_ws + (size_t)OUT_F * IN_F * 2); // 32 MB

    prep_kernel<<<dim3(DEQ_BLOCKS + CVT_BLOCKS), dim3(256), 0, stream>>>(
        qweight, qzeros, scales, x, W, Abf);
    gemm_bt<<<dim3(OUT_F / 128, TOKENS / 128), dim3(256), 0, stream>>>(
        Abf, W, bias, out);
}